// Round 22
// baseline (189.235 us; speedup 1.0000x reference)
//
#include <hip/hip_runtime.h>
#include <hip/hip_bf16.h>
#include <math.h>

typedef __hip_bfloat16 bf16;
typedef __attribute__((ext_vector_type(8))) short bf16x8;
typedef __attribute__((ext_vector_type(4))) float f32x4;

#define N_    2
#define D_    192
#define T_    8
#define H_    48
#define W_    48
#define HW_   2304
#define NPOS  36864
#define BUF_ELEMS 7077888    // NPOS*192

// WF (f32 weight arena) element offsets
#define OFF_SOFFW 0
#define OFF_SOFFB 12288
#define OFF_SAWW  12352
#define OFF_SAWB  18496
#define OFF_SVW   18528
#define OFF_SVB   55392
#define OFF_SOW   55584
#define OFF_SOB   92448
#define OFF_TOFFW 92640
#define OFF_TOFFB 98784
#define OFF_TAWW  98816
#define OFF_TAWB  104960
#define OFF_TVW   104992
#define OFF_TVB   141856
#define OFF_TOW   142048
#define OFF_TOB   178912
#define OFF_LN1G  179104
#define OFF_LN1B  179296
#define OFF_LN2G  179488
#define OFF_LN2B  179680
#define OFF_LN3G  179872
#define OFF_LN3B  180064
#define OFF_LIN1W 180256
#define OFF_LIN1B 253984
#define OFF_LIN2W 254176
#define OFF_LIN2B 291040
#define OFF_CONVB 291232
#define WF_TOTAL  291424

// packed-B arena (bf16 elements) offsets
#define PB_SCOMB 0         // 192x288 (v|off|aw)
#define PB_SOW   55296     // 192x192
#define PB_TCOMB 92160     // 192x256 (v|off|aw)
#define PB_TOW   141312
#define PB_LIN1  178176    // 384x192
#define PB_CONV  251904    // 384x192
#define PB_LIN2  325632    // 192x192
#define PB_TOTAL 362496

static __device__ __forceinline__ float b2f(bf16 v){ return __bfloat162float(v); }
static __device__ __forceinline__ bf16  f2b(float v){ return __float2bfloat16(v); }
static __device__ __forceinline__ float lo16(unsigned u){
  unsigned v = u<<16; return *(float*)&v;
}
static __device__ __forceinline__ float hi16(unsigned u){
  unsigned v = u & 0xFFFF0000u; return *(float*)&v;
}
static __device__ __forceinline__ unsigned pk2(float a, float b){
  bf16 x = f2b(a), y = f2b(b);
  return (unsigned)*(unsigned short*)&x | ((unsigned)*(unsigned short*)&y << 16);
}
static __device__ __forceinline__ int detect_bf(const void* ln1g){
  unsigned u = *(const unsigned*)ln1g;
  return __builtin_amdgcn_readfirstlane(((u & 0xFFFFu) != 0u) ? 1 : 0);
}
// 16B-chunk XOR swizzle
static __device__ __forceinline__ int swz8(int ch, int r){ return ch ^ (r & 7); }

// ---- convert all weights (27 regions) to f32 arena; 1 elem/thread ----
struct KPtrs { const void* p[27]; };
static __device__ const int WSZ[27] = {12288,64,6144,32,36864,192,36864,192,
  6144,32,6144,32,36864,192,36864,192, 192,192,192,192,192,192, 73728,192,36864,192, 192};

__global__ void k_cvtw(KPtrs P, float* __restrict__ WF, const void* __restrict__ ln1g){
  int bf = detect_bf(ln1g);
  int gid = blockIdx.x*256 + threadIdx.x;
  if (gid >= WF_TOTAL) return;
  int e = 0, off = 0;
  while (gid >= off + WSZ[e]){ off += WSZ[e]; ++e; }
  int i = gid - off;
  WF[gid] = bf ? b2f(((const bf16*)P.p[e])[i]) : ((const float*)P.p[e])[i];
}

// ---- transpose conv_w ----
__global__ void k_wt(const void* __restrict__ W, float* __restrict__ Wt, const void* __restrict__ ln1g){
  int bf = detect_bf(ln1g);
  int i = blockIdx.x*256 + threadIdx.x;
  if (i < 384*192){
    int c = i/192, o = i%192;
    Wt[i] = bf ? b2f(((const bf16*)W)[o*384+c]) : ((const float*)W)[o*384+c];
  }
}

// ---- pack B fragments for 7 matrices ----
__global__ void k_packB(const float* __restrict__ WF, const float* __restrict__ Wt,
                        bf16* __restrict__ PB){
  const int NB[7]  = {108,72,96,72,144,144,72};
  const int NT[7]  = {18,12,16,12,12,12,12};
  const int DST[7] = {PB_SCOMB, PB_SOW, PB_TCOMB, PB_TOW, PB_LIN1, PB_CONV, PB_LIN2};
  int bid = blockIdx.x, e = 0, start = 0;
  while (e < 6 && bid >= start + NB[e]){ start += NB[e]; ++e; }
  int local = bid - start;
  int nt = local % NT[e], kt = local / NT[e];
  int l = threadIdx.x;
  int k0 = kt*32 + (l>>4)*8, n0 = nt*16 + (l&15);
  bf16* D = PB + DST[e] + ((long)(kt*NT[e]+nt)*64 + l)*8;
  #pragma unroll
  for (int i=0;i<8;++i){
    int k = k0 + i;
    float v;
    if (e==0){
      if (n0<192)      v = WF[OFF_SVW  + k*192 + n0];
      else if (n0<256) v = WF[OFF_SOFFW+ k*64  + (n0-192)];
      else             v = WF[OFF_SAWW + k*32  + (n0-256)];
    } else if (e==1)   v = WF[OFF_SOW  + k*192 + n0];
    else if (e==2){
      if (n0<192)      v = WF[OFF_TVW  + k*192 + n0];
      else if (n0<224) v = WF[OFF_TOFFW+ k*32  + (n0-192)];
      else             v = WF[OFF_TAWW + k*32  + (n0-224)];
    } else if (e==3)   v = WF[OFF_TOW  + k*192 + n0];
    else if (e==4)     v = WF[OFF_LIN1W+ k*192 + n0];
    else if (e==5)     v = Wt[k*192 + n0];
    else               v = WF[OFF_LIN2W+ k*192 + n0];
    D[i] = f2b(v);
  }
}

// ---- MFMA GEMM (lin1): LDS-staged swizzled A; MODE 1 = FFN gather + GELU ----
template<int KTOT, int MODE, int CF32>
__global__ void __launch_bounds__(256) k_gemm(const bf16* __restrict__ A0, const bf16* __restrict__ A1,
      const bf16* __restrict__ Bp, const float* __restrict__ bias, void* __restrict__ C_){
  __shared__ bf16 sA[64*KTOT];
  const int NCH = KTOT/8;
  int tid = threadIdx.x;
  int r0 = blockIdx.x*64;
  for (int i=tid; i<64*NCH; i+=256){
    int r = i/NCH, ch = i - r*NCH;
    int grow;
    if (MODE==1){
      int q = r0+r, f = q>>1, n2 = q&1;
      int t2 = f/HW_, hw2 = f - t2*HW_;
      grow = hw2*16 + t2*2 + n2;
    } else grow = r0+r;
    const bf16* src = (MODE==1 && ch>=24) ? (A1 + (long)grow*192 + (ch-24)*8)
                                          : (A0 + (long)grow*192 + ch*8);
    *(bf16x8*)(sA + r*KTOT + swz8(ch,r)*8) = *(const bf16x8*)src;
  }
  __syncthreads();
  int wid = tid>>6, lane = tid&63;
  int m16 = lane&15, kg = lane>>4;
  f32x4 acc[4][3];
  #pragma unroll
  for (int mi=0;mi<4;++mi)
    #pragma unroll
    for (int ni=0;ni<3;++ni) acc[mi][ni] = (f32x4){0.f,0.f,0.f,0.f};

  const int NKT = KTOT/32;
  for (int kt=0; kt<NKT; ++kt){
    bf16x8 b[3];
    #pragma unroll
    for (int ni=0;ni<3;++ni){
      int nt = wid*3 + ni;
      b[ni] = *(const bf16x8*)(Bp + ((long)(kt*12+nt)*64 + lane)*8);
    }
    bf16x8 a[4];
    #pragma unroll
    for (int mi=0;mi<4;++mi){
      int row = mi*16 + m16;
      a[mi] = *(const bf16x8*)(sA + row*KTOT + swz8(kt*4+kg,row)*8);
    }
    #pragma unroll
    for (int mi=0;mi<4;++mi)
      #pragma unroll
      for (int ni=0;ni<3;++ni)
        acc[mi][ni] = __builtin_amdgcn_mfma_f32_16x16x32_bf16(a[mi], b[ni], acc[mi][ni], 0,0,0);
  }
  const float IS2 = 0.70710678118654752f;
  #pragma unroll
  for (int mi=0;mi<4;++mi)
    #pragma unroll
    for (int ni=0;ni<3;++ni){
      int col = (wid*3+ni)*16 + m16;
      float bv = bias[col];
      #pragma unroll
      for (int rg=0;rg<4;++rg){
        int row = r0 + mi*16 + kg*4 + rg;
        float v = acc[mi][ni][rg] + bv;
        if (MODE==1) v = 0.5f*v*(1.f+erff(v*IS2));
        if (CF32) ((float*)C_)[(long)row*192 + col] = v;
        else      ((bf16*)C_)[(long)row*192 + col] = f2b(v);
      }
    }
}

// ---- combined MFMA GEMM (spatial): LDS-staged f32 A; V + off/aw logits ----
template<int NWAVES, int NTW, int NO>
__global__ void __launch_bounds__(NWAVES*64) k_gemmC(const float* __restrict__ A,
      const bf16* __restrict__ Bp, const float* __restrict__ biasV,
      const float* __restrict__ biasO, const float* __restrict__ biasA,
      bf16* __restrict__ Cv, float* __restrict__ Coa){
  __shared__ bf16 sA[64*192];
  const int NT_TOT = NWAVES*NTW;
  const int NOA = NT_TOT*16 - 192;
  int tid = threadIdx.x;
  int r0 = blockIdx.x*64;
  for (int i=tid; i<64*48; i+=NWAVES*64){
    int r = i/48, c4 = i - r*48;
    float4 v = *(const float4*)(A + (long)(r0+r)*192 + c4*4);
    bf16* dst = sA + r*192 + swz8(c4>>1, r)*8 + (c4&1)*4;
    dst[0]=f2b(v.x); dst[1]=f2b(v.y); dst[2]=f2b(v.z); dst[3]=f2b(v.w);
  }
  __syncthreads();
  int wid = tid>>6, lane = tid&63;
  int m16 = lane&15, kg = lane>>4;
  f32x4 acc[4][NTW];
  #pragma unroll
  for (int mi=0;mi<4;++mi)
    #pragma unroll
    for (int ni=0;ni<NTW;++ni) acc[mi][ni] = (f32x4){0.f,0.f,0.f,0.f};
  for (int kt=0; kt<6; ++kt){
    bf16x8 b[NTW];
    #pragma unroll
    for (int ni=0;ni<NTW;++ni){
      int nt = wid*NTW + ni;
      b[ni] = *(const bf16x8*)(Bp + ((long)(kt*NT_TOT+nt)*64 + lane)*8);
    }
    bf16x8 a[4];
    #pragma unroll
    for (int mi=0;mi<4;++mi){
      int row = mi*16 + m16;
      a[mi] = *(const bf16x8*)(sA + row*192 + swz8(kt*4+kg,row)*8);
    }
    #pragma unroll
    for (int mi=0;mi<4;++mi)
      #pragma unroll
      for (int ni=0;ni<NTW;++ni)
        acc[mi][ni] = __builtin_amdgcn_mfma_f32_16x16x32_bf16(a[mi], b[ni], acc[mi][ni], 0,0,0);
  }
  #pragma unroll
  for (int mi=0;mi<4;++mi)
    #pragma unroll
    for (int ni=0;ni<NTW;++ni){
      int col = (wid*NTW+ni)*16 + m16;
      #pragma unroll
      for (int rg=0;rg<4;++rg){
        int row = r0 + mi*16 + kg*4 + rg;
        float v = acc[mi][ni][rg];
        if (col < 192)           Cv[(long)row*192 + col] = f2b(v + biasV[col]);
        else if (col < 192+NO)   Coa[(long)row*NOA + (col-192)] = v + biasO[col-192];
        else                     Coa[(long)row*NOA + (col-192)] = v + biasA[col-192-NO];
      }
    }
}

// ---- conv as MFMA GEMM ----
__global__ void __launch_bounds__(256) k_convm(const void* __restrict__ x, const void* __restrict__ fuse,
      const bf16* __restrict__ Bp, const float* __restrict__ bias, float* __restrict__ B0,
      const void* __restrict__ ln1g){
  __shared__ bf16 sA[64*384];
  int bf = detect_bf(ln1g);
  int bid = blockIdx.x;
  int n = bid/(8*36), rm = bid%(8*36);
  int t = rm/36, hb = rm%36;
  int hw0 = hb*64;
  int tid = threadIdx.x;
  if (bf){
    for (int i=tid; i<384*64; i+=256){
      int c = i>>6, j = i&63;
      long idx = (c<192) ? ((long)((n*192+c)*8 + t)*HW_ + hw0 + j)
                         : ((long)(n*192+(c-192))*HW_ + hw0 + j);
      bf16 v = ((const bf16*)((c<192)?x:fuse))[idx];
      sA[j*384 + swz8(c>>3, j)*8 + (c&7)] = v;
    }
  } else {
    for (int i=tid; i<384*64; i+=256){
      int c = i>>6, j = i&63;
      long idx = (c<192) ? ((long)((n*192+c)*8 + t)*HW_ + hw0 + j)
                         : ((long)(n*192+(c-192))*HW_ + hw0 + j);
      float v = ((const float*)((c<192)?x:fuse))[idx];
      sA[j*384 + swz8(c>>3, j)*8 + (c&7)] = f2b(v);
    }
  }
  __syncthreads();
  int wid = tid>>6, lane = tid&63;
  int m16 = lane&15, kg = lane>>4;
  f32x4 acc[4][3];
  #pragma unroll
  for (int mi=0;mi<4;++mi)
    #pragma unroll
    for (int ni=0;ni<3;++ni) acc[mi][ni] = (f32x4){0.f,0.f,0.f,0.f};
  for (int kt=0; kt<12; ++kt){
    bf16x8 b[3];
    #pragma unroll
    for (int ni=0;ni<3;++ni){
      int nt = wid*3 + ni;
      b[ni] = *(const bf16x8*)(Bp + ((long)(kt*12+nt)*64 + lane)*8);
    }
    bf16x8 a[4];
    #pragma unroll
    for (int mi=0;mi<4;++mi){
      int row = mi*16 + m16;
      a[mi] = *(const bf16x8*)(&sA[row*384 + swz8(kt*4+kg,row)*8]);
    }
    #pragma unroll
    for (int mi=0;mi<4;++mi)
      #pragma unroll
      for (int ni=0;ni<3;++ni)
        acc[mi][ni] = __builtin_amdgcn_mfma_f32_16x16x32_bf16(a[mi], b[ni], acc[mi][ni], 0,0,0);
  }
  long posbase = (long)(n*8+t)*HW_ + hw0;
  #pragma unroll
  for (int mi=0;mi<4;++mi)
    #pragma unroll
    for (int ni=0;ni<3;++ni){
      int col = (wid*3+ni)*16 + m16;
      float bv = bias[col];
      #pragma unroll
      for (int rg=0;rg<4;++rg){
        int row = mi*16 + kg*4 + rg;
        B0[(posbase + row)*192 + col] = acc[mi][ni][rg] + bv;
      }
    }
}

// ---- fused spatial tail: sampling + o-proj MFMA + residual + LN -> XS ----
__global__ void __launch_bounds__(256) k_sfuse(const float* __restrict__ OA, const bf16* __restrict__ V,
    const bf16* __restrict__ Bp, const float* __restrict__ biasO,
    const float* __restrict__ X, const float* __restrict__ g, const float* __restrict__ bta,
    bf16* __restrict__ outXS){
  __shared__ char smem[32768 + 12288];   // tup(32KB)|yb(24.7KB alias) + sA(12KB)
  __shared__ float mrs[32][2];
  float (*tup)[8] = (float(*)[8])smem;
  float (*yb)[193] = (float(*)[193])smem;
  bf16* sA = (bf16*)(smem + 32768);
  int r0 = blockIdx.x*32, tid = threadIdx.x;
  int nt = r0 / HW_;
  for (int i=tid; i<512; i+=256){
    int row = i>>4, head = i&15;
    int l = (r0+row) % HW_;
    int iy = l/48, jx = l%48;
    const float* oa = OA + (long)(r0+row)*96;
    float l0 = oa[64+head*2], l1 = oa[64+head*2+1];
    float m = fmaxf(l0,l1);
    float e0 = __expf(l0-m), e1 = __expf(l1-m);
    float inv = 1.f/(e0+e1);
    const float SC = 48.0f/47.0f;
    #pragma unroll
    for (int p=0;p<2;++p){
      float aw = (p==0?e0:e1)*inv;
      float fx = iy*SC + oa[head*4+p*2+0] - 0.5f;
      float fy = jx*SC + oa[head*4+p*2+1] - 0.5f;
      float x0f = floorf(fx), y0f = floorf(fy);
      float wx = fx-x0f, wy = fy-y0f;
      int x0 = (int)x0f, y0 = (int)y0f;
      int x1 = x0+1, y1 = y0+1;
      bool vx0 = (x0>=0 && x0<48), vx1 = (x1>=0 && x1<48);
      bool vy0 = (y0>=0 && y0<48), vy1 = (y1>=0 && y1<48);
      int cx0 = min(max(x0,0),47), cx1 = min(max(x1,0),47);
      int cy0 = min(max(y0,0),47), cy1 = min(max(y1,0),47);
      float* tp = tup[row*32 + head*2 + p];
      tp[0] = (vx0&&vy0) ? aw*(1.f-wx)*(1.f-wy) : 0.f;
      tp[1] = (vx1&&vy0) ? aw*wx*(1.f-wy)       : 0.f;
      tp[2] = (vx0&&vy1) ? aw*(1.f-wx)*wy       : 0.f;
      tp[3] = (vx1&&vy1) ? aw*wx*wy             : 0.f;
      tp[4] = (float)(cy0*48+cx0);
      tp[5] = (float)(cy0*48+cx1);
      tp[6] = (float)(cy1*48+cx0);
      tp[7] = (float)(cy1*48+cx1);
    }
  }
  __syncthreads();
  const unsigned* vbu = (const unsigned*)(V + (long)nt*HW_*192);
  for (int it=tid; it<3072; it+=256){
    int row = it/96, cp = it - row*96;
    int head = cp/6;
    float a0 = 0.f, a1 = 0.f;
    #pragma unroll
    for (int p=0;p<2;++p){
      const float* tp = tup[row*32 + head*2 + p];
      #pragma unroll
      for (int c=0;c<4;++c){
        float w = tp[c];
        int idx = (int)tp[4+c];
        unsigned u = vbu[idx*96 + cp];
        a0 += w*lo16(u);
        a1 += w*hi16(u);
      }
    }
    *(unsigned*)(sA + row*192 + swz8(cp>>2,row)*8 + (cp&3)*2) = pk2(a0,a1);
  }
  __syncthreads();
  int wid = tid>>6, lane = tid&63;
  int m16 = lane&15, kg = lane>>4;
  f32x4 acc[2][3];
  #pragma unroll
  for (int mi=0;mi<2;++mi)
    #pragma unroll
    for (int ni=0;ni<3;++ni) acc[mi][ni] = (f32x4){0.f,0.f,0.f,0.f};
  for (int kt=0; kt<6; ++kt){
    bf16x8 b[3];
    #pragma unroll
    for (int ni=0;ni<3;++ni){
      int ntb = wid*3 + ni;
      b[ni] = *(const bf16x8*)(Bp + ((long)(kt*12+ntb)*64 + lane)*8);
    }
    bf16x8 a[2];
    #pragma unroll
    for (int mi=0;mi<2;++mi){
      int row = mi*16 + m16;
      a[mi] = *(const bf16x8*)(sA + row*192 + swz8(kt*4+kg,row)*8);
    }
    #pragma unroll
    for (int mi=0;mi<2;++mi)
      #pragma unroll
      for (int ni=0;ni<3;++ni)
        acc[mi][ni] = __builtin_amdgcn_mfma_f32_16x16x32_bf16(a[mi], b[ni], acc[mi][ni], 0,0,0);
  }
  __syncthreads();
  #pragma unroll
  for (int mi=0;mi<2;++mi)
    #pragma unroll
    for (int ni=0;ni<3;++ni){
      int col = (wid*3+ni)*16 + m16;
      float bv = biasO[col];
      #pragma unroll
      for (int rg=0;rg<4;++rg){
        int lr = mi*16 + kg*4 + rg;
        yb[lr][col] = acc[mi][ni][rg] + bv + X[(long)(r0+lr)*192 + col];
      }
    }
  __syncthreads();
  for (int rr=0; rr<8; ++rr){
    int row = wid*8 + rr;
    float s=0.f, s2=0.f;
    #pragma unroll
    for (int e=0;e<3;++e){
      float v = yb[row][lane*3+e];
      s += v; s2 += v*v;
    }
    #pragma unroll
    for (int off=32; off>0; off>>=1){ s += __shfl_xor(s,off); s2 += __shfl_xor(s2,off); }
    if (lane==0){
      float mean = s*(1.f/192.f);
      mrs[row][0] = mean;
      mrs[row][1] = rsqrtf(s2*(1.f/192.f) - mean*mean + 1e-5f);
    }
  }
  __syncthreads();
  for (int i=tid; i<3072; i+=256){
    int row = i/96, cp = i - row*96;
    float mean = mrs[row][0], rstd = mrs[row][1];
    int c0 = cp*2, c1 = c0+1;
    float v0 = (yb[row][c0]-mean)*rstd*g[c0] + bta[c0];
    float v1 = (yb[row][c1]-mean)*rstd*g[c1] + bta[c1];
    ((unsigned*)outXS)[(long)(r0+row)*96 + cp] = pk2(v0,v1);
  }
}

// ---- full temporal path, 2-token tile; residual carried in registers (no F1/F2) ----
// arena: A: srcF[0,12288) f32 | sST[12288,18432)
//        B out: sV[0,6400) bf16 s200 | slog[6400,10752) f32 s68
//        C out: tup[18432,24576) [512][3]
//        D out: sA = sST slot
//        post-E: yb[0,12288) f32 [16][192]
__global__ void __launch_bounds__(256) k_tpath(const float* __restrict__ S0,
    const bf16* __restrict__ BpC, const float* __restrict__ biasV,
    const float* __restrict__ biasOf, const float* __restrict__ biasAw,
    const bf16* __restrict__ BpO, const float* __restrict__ biasO,
    const float* __restrict__ g, const float* __restrict__ bta,
    bf16* __restrict__ outXT){
  __shared__ char smem[24576];
  __shared__ float mrs[16][2];
  float*    srcF = (float*)smem;                    // [2][8][192] linear
  bf16*     sST  = (bf16*)(smem + 12288);           // sXT then sA, 6K
  bf16*     sV   = (bf16*)smem;                     // stride 200, [0,6400)
  float*    slog = (float*)(smem + 6400);           // stride 68, 16 rows
  float (*tup)[3] = (float(*)[3])(smem + 18432);    // [512][3]
  float*    yb   = (float*)smem;                    // [16][192] post-E
  int bid = blockIdx.x, tid = threadIdx.x;
  int b0 = bid*2, r0 = bid*16;
  int n = b0 / HW_, hw0 = b0 - n*HW_;
  int wid = tid>>6, lane = tid&63;
  int m16 = lane&15, kg = lane>>4;

  // phase A1: coalesced float4 stage of S0 source rows (linear layout)
  for (int i=tid; i<768; i+=256){
    int j = i/384, rem = i - j*384;
    int t = rem/48, c4 = rem - t*48;
    float4 v = *(const float4*)(S0 + ((long)((n*8+t)*HW_) + hw0+j)*192 + c4*4);
    *(float4*)(srcF + j*1536 + t*192 + c4*4) = v;
  }
  __syncthreads();
  // phase A2: transposed write to swizzled sST; residual kept in named registers
  float rsv0[8], rsv1[8];
  {
    int idx0 = tid;                       // always < 384
    int lrow = idx0/24, ch = idx0 - lrow*24;
    int j = lrow>>3, tau = lrow&7;
    int o = tau*24 + ch;
    const float* sp = srcF + j*1536 + o;
    union { bf16 h[8]; bf16x8 v; } u;
    #pragma unroll
    for (int t=0;t<8;++t){ float f = sp[t*192]; rsv0[t] = f; u.h[t] = f2b(f); }
    *(bf16x8*)(sST + lrow*192 + swz8(ch,lrow)*8) = u.v;
  }
  if (tid < 128){
    int idx1 = tid + 256;
    int lrow = idx1/24, ch = idx1 - lrow*24;
    int j = lrow>>3, tau = lrow&7;
    int o = tau*24 + ch;
    const float* sp = srcF + j*1536 + o;
    union { bf16 h[8]; bf16x8 v; } u;
    #pragma unroll
    for (int t=0;t<8;++t){ float f = sp[t*192]; rsv1[t] = f; u.h[t] = f2b(f); }
    *(bf16x8*)(sST + lrow*192 + swz8(ch,lrow)*8) = u.v;
  }
  __syncthreads();
  // phase B: MFMA vs TCOMB (V -> sV s200, logits -> slog s68); 16 rows = 1 m-tile
  {
    f32x4 acc[4];
    #pragma unroll
    for (int ni=0;ni<4;++ni) acc[ni] = (f32x4){0.f,0.f,0.f,0.f};
    for (int kt=0; kt<6; ++kt){
      bf16x8 b[4];
      #pragma unroll
      for (int ni=0;ni<4;++ni){
        int ntb = wid*4 + ni;
        b[ni] = *(const bf16x8*)(BpC + ((long)(kt*16+ntb)*64 + lane)*8);
      }
      bf16x8 a = *(const bf16x8*)(sST + m16*192 + swz8(kt*4+kg,m16)*8);
      #pragma unroll
      for (int ni=0;ni<4;++ni)
        acc[ni] = __builtin_amdgcn_mfma_f32_16x16x32_bf16(a, b[ni], acc[ni], 0,0,0);
    }
    __syncthreads();   // srcF reads retired (sV/slog overwrite that slot)
    #pragma unroll
    for (int ni=0;ni<4;++ni){
      int col = (wid*4+ni)*16 + m16;
      #pragma unroll
      for (int rg=0;rg<4;++rg){
        int lr = kg*4 + rg;
        float v = acc[ni][rg];
        if (col < 192)      sV[lr*200 + col] = f2b(v + biasV[col]);
        else if (col < 224) slog[lr*68 + (col-192)] = v + biasOf[col-192];
        else                slog[lr*68 + (col-192)] = v + biasAw[col-224];
      }
    }
  }
  __syncthreads();
  // phase C: coords (16 rows x 8 heads = 128 items)
  if (tid < 128){
    int row = tid>>3, head = tid&7;
    int tau = row & 7;
    float pref = tau*(8.0f/7.0f) - 0.5f;
    const float* ot = slog + row*68;
    float l0=ot[32+head*4], l1=ot[32+head*4+1], l2=ot[32+head*4+2], l3=ot[32+head*4+3];
    float m = fmaxf(fmaxf(l0,l1), fmaxf(l2,l3));
    float e0=__expf(l0-m), e1=__expf(l1-m), e2=__expf(l2-m), e3=__expf(l3-m);
    float inv = 1.f/(e0+e1+e2+e3);
    float ee[4] = {e0,e1,e2,e3};
    #pragma unroll
    for (int p=0;p<4;++p){
      float aw = ee[p]*inv;
      float fp = pref + ot[head*4+p];
      float p0f = floorf(fp);
      float wp = fp - p0f;
      int p0 = (int)p0f, p1 = p0+1;
      float* tp = tup[row*32 + head*4 + p];
      tp[0] = (p0>=0 && p0<8) ? aw*(1.f-wp) : 0.f;
      tp[1] = (p1>=0 && p1<8) ? aw*wp       : 0.f;
      tp[2] = (float)(min(max(p0,0),7)*8 + min(max(p1,0),7));
    }
  }
  __syncthreads();
  // phase D: sampling -> swizzled sA (sST slot)
  {
    const unsigned* sVu = (const unsigned*)sV;   // row stride 100 uints
    for (int it=tid; it<1536; it+=256){
      int row = it/96, cp = it - row*96;
      int head = cp/12;
      const unsigned* vb = sVu + (row>>3)*800;
      float a0 = 0.f, a1 = 0.f;
      #pragma unroll
      for (int p=0;p<4;++p){
        const float* tp = tup[row*32 + head*4 + p];
        int pk = (int)tp[2];
        unsigned u0 = vb[(pk>>3)*100 + cp];
        unsigned u1 = vb[(pk&7)*100 + cp];
        a0 += tp[0]*lo16(u0) + tp[1]*lo16(u1);
        a1 += tp[0]*hi16(u0) + tp[1]*hi16(u1);
      }
      *(unsigned*)(sST + row*192 + swz8(cp>>2,row)*8 + (cp&3)*2) = pk2(a0,a1);
    }
  }
  __syncthreads();
  // phase E: o-proj MFMA
  f32x4 acc2[3];
  #pragma unroll
  for (int ni=0;ni<3;++ni) acc2[ni] = (f32x4){0.f,0.f,0.f,0.f};
  for (int kt=0; kt<6; ++kt){
    bf16x8 b[3];
    #pragma unroll
    for (int ni=0;ni<3;++ni){
      int ntb = wid*3 + ni;
      b[ni] = *(const bf16x8*)(BpO + ((long)(kt*12+ntb)*64 + lane)*8);
    }
    bf16x8 a = *(const bf16x8*)(sST + m16*192 + swz8(kt*4+kg,m16)*8);
    #pragma unroll
    for (int ni=0;ni<3;++ni)
      acc2[ni] = __builtin_amdgcn_mfma_f32_16x16x32_bf16(a, b[ni], acc2[ni], 0,0,0);
  }
  __syncthreads();   // all earlier regions dead; yb takes over
  // phase F: write register-carried residual into yb [16][192]
  {
    int idx0 = tid;
    int lrow = idx0/24, ch = idx0 - lrow*24;
    float* dp = yb + lrow*192 + ch*8;
    #pragma unroll
    for (int t=0;t<8;++t) dp[t] = rsv0[t];
  }
  if (tid < 128){
    int idx1 = tid + 256;
    int lrow = idx1/24, ch = idx1 - lrow*24;
    float* dp = yb + lrow*192 + ch*8;
    #pragma unroll
    for (int t=0;t<8;++t) dp[t] = rsv1[t];
  }
  __syncthreads();
  // add o-proj + bias
  #pragma unroll
  for (int ni=0;ni<3;++ni){
    int col = (wid*3+ni)*16 + m16;
    float bv = biasO[col];
    #pragma unroll
    for (int rg=0;rg<4;++rg){
      int lr = kg*4 + rg;
      yb[lr*192 + col] += acc2[ni][rg] + bv;
    }
  }
  __syncthreads();
  // phase G: LN + write XT
  for (int rr=0; rr<4; ++rr){
    int row = wid*4 + rr;
    float s=0.f, s2=0.f;
    #pragma unroll
    for (int e=0;e<3;++e){
      float v = yb[row*192 + lane*3+e];
      s += v; s2 += v*v;
    }
    #pragma unroll
    for (int off=32; off>0; off>>=1){ s += __shfl_xor(s,off); s2 += __shfl_xor(s2,off); }
    if (lane==0){
      float mean = s*(1.f/192.f);
      mrs[row][0] = mean;
      mrs[row][1] = rsqrtf(s2*(1.f/192.f) - mean*mean + 1e-5f);
    }
  }
  __syncthreads();
  for (int i=tid; i<1536; i+=256){
    int row = i/96, cp = i - row*96;
    float mean = mrs[row][0], rstd = mrs[row][1];
    int c0 = cp*2, c1 = c0+1;
    float v0 = (yb[row*192+c0]-mean)*rstd*g[c0] + bta[c0];
    float v1 = (yb[row*192+c1]-mean)*rstd*g[c1] + bta[c1];
    ((unsigned*)outXT)[(long)(r0+row)*96 + cp] = pk2(v0,v1);
  }
}

// ---- final fused: 32 pos/block; bf16 hid staged; MFMA lin2 + residual + LN + scatter ----
__global__ void __launch_bounds__(256) k_final3(const float* __restrict__ B0, const bf16* __restrict__ hid,
    const bf16* __restrict__ Bp, const float* __restrict__ bias2,
    const float* __restrict__ g, const float* __restrict__ bta,
    void* __restrict__ out, const void* __restrict__ ln1g){
  __shared__ float yb[32][193];
  __shared__ float mrs[32][2];
  bf16* sA = (bf16*)&yb[0][0];
  int bf = detect_bf(ln1g);
  int pos0 = blockIdx.x*32;
  int tid = threadIdx.x, wid = tid>>6, lane = tid&63;
  int m16 = lane&15, kg = lane>>4;
  int n2 = pos0/(T_*HW_), rem0 = pos0%(T_*HW_);
  long qrow0 = (long)rem0*2 + n2;
  for (int i=tid; i<32*24; i+=256){
    int r = i/24, ch = i - r*24;
    *(bf16x8*)(sA + r*192 + swz8(ch,r)*8) =
        *(const bf16x8*)(hid + (qrow0 + r*2)*192 + ch*8);
  }
  __syncthreads();
  f32x4 acc[2][3];
  #pragma unroll
  for (int mi=0;mi<2;++mi)
    #pragma unroll
    for (int ni=0;ni<3;++ni) acc[mi][ni] = (f32x4){0.f,0.f,0.f,0.f};
  for (int kt=0; kt<6; ++kt){
    bf16x8 b[3];
    #pragma unroll
    for (int ni=0;ni<3;++ni){
      int nt = wid*3 + ni;
      b[ni] = *(const bf16x8*)(Bp + ((long)(kt*12+nt)*64 + lane)*8);
    }
    bf16x8 a[2];
    #pragma unroll
    for (int mi=0;mi<2;++mi){
      int row = mi*16 + m16;
      a[mi] = *(const bf16x8*)(sA + row*192 + swz8(kt*4+kg,row)*8);
    }
    #pragma unroll
    for (int mi=0;mi<2;++mi)
      #pragma unroll
      for (int ni=0;ni<3;++ni)
        acc[mi][ni] = __builtin_amdgcn_mfma_f32_16x16x32_bf16(a[mi], b[ni], acc[mi][ni], 0,0,0);
  }
  __syncthreads();
  #pragma unroll
  for (int mi=0;mi<2;++mi)
    #pragma unroll
    for (int ni=0;ni<3;++ni){
      int col = (wid*3+ni)*16 + m16;
      float bv = bias2[col];
      #pragma unroll
      for (int rg=0;rg<4;++rg){
        int lr = mi*16 + kg*4 + rg;
        yb[lr][col] = acc[mi][ni][rg] + bv + B0[(long)(pos0+lr)*192 + col];
      }
    }
  __syncthreads();
  for (int rr=0; rr<8; ++rr){
    int row = wid*8 + rr;
    float s=0.f, s2=0.f;
    #pragma unroll
    for (int e=0;e<3;++e){
      float v = yb[row][lane*3+e];
      s += v; s2 += v*v;
    }
    #pragma unroll
    for (int off=32; off>0; off>>=1){ s += __shfl_xor(s,off); s2 += __shfl_xor(s2,off); }
    if (lane==0){
      float mean = s*(1.f/192.f);
      mrs[row][0] = mean;
      mrs[row][1] = rsqrtf(s2*(1.f/192.f) - mean*mean + 1e-5f);
    }
  }
  __syncthreads();
  int t2 = rem0/HW_, hw0 = rem0%HW_;
  int j = lane & 31;
  float mean = mrs[j][0], rstd = mrs[j][1];
  for (int cc=0; cc<48; cc+=2){
    int c = wid*48 + cc + (lane>>5);
    float val = (yb[j][c]-mean)*rstd*g[c] + bta[c];
    long idx = ((long)(n2*192 + c)*8 + t2)*HW_ + hw0 + j;
    if (bf) ((bf16*)out)[idx] = f2b(val);
    else    ((float*)out)[idx] = val;
  }
}

extern "C" void kernel_launch(void* const* d_in, const int* in_sizes, int n_in,
                              void* d_out, int out_size, void* d_ws, size_t ws_size,
                              hipStream_t stream){
  const void* x      = d_in[0];
  const void* fuse   = d_in[1];
  const void* conv_w = d_in[2];
  const void* ln1g_raw = d_in[20];

  float* S0f = (float*)d_ws;
  float* WS2 = S0f + BUF_ELEMS;          // Vb bf16 (1st half) + OA f32 (2nd half); HID aliases
  bf16*  Vb  = (bf16*)WS2;
  float* OA  = WS2 + BUF_ELEMS/2;
  bf16*  HID = (bf16*)WS2;
  float* WS4 = WS2 + BUF_ELEMS;          // XS
  bf16*  XS  = (bf16*)WS4;
  float* WS5 = WS4 + BUF_ELEMS/2;        // XT
  bf16*  XT  = (bf16*)WS5;
  float* WF  = WS5 + BUF_ELEMS/2;
  float* Wt  = WF + WF_TOTAL;
  bf16*  PB  = (bf16*)(Wt + 384*192);

  KPtrs P;
  for (int i=0;i<26;++i) P.p[i] = d_in[4+i];
  P.p[26] = d_in[3];   // conv_b

  k_cvtw <<<(WF_TOTAL+255)/256, 256, 0, stream>>>(P, WF, ln1g_raw);
  k_wt   <<<288, 256, 0, stream>>>(conv_w, Wt, ln1g_raw);
  k_packB<<<708, 64, 0, stream>>>(WF, Wt, PB);

  k_convm<<<576, 256, 0, stream>>>(x, fuse, PB+PB_CONV, WF+OFF_CONVB, S0f, ln1g_raw);

  // spatial deformable attention
  k_gemmC<6,3,64><<<576, 384, 0, stream>>>(S0f, PB+PB_SCOMB, WF+OFF_SVB, WF+OFF_SOFFB, WF+OFF_SAWB, Vb, OA);
  k_sfuse<<<NPOS/32, 256, 0, stream>>>(OA, Vb, PB+PB_SOW, WF+OFF_SOB, S0f,
                                       WF+OFF_LN1G, WF+OFF_LN1B, XS);

  // temporal deformable attention: single fused kernel, 2-token tiles
  k_tpath<<<NPOS/16, 256, 0, stream>>>(S0f, PB+PB_TCOMB, WF+OFF_TVB, WF+OFF_TOFFB, WF+OFF_TAWB,
                                       PB+PB_TOW, WF+OFF_TOB, WF+OFF_LN2G, WF+OFF_LN2B, XT);

  // FFN (gather + GELU, bf16 out) + fused final
  k_gemm<384,1,0><<<576, 256, 0, stream>>>(XT, XS, PB+PB_LIN1, WF+OFF_LIN1B, HID);
  k_final3<<<NPOS/32, 256, 0, stream>>>(S0f, HID, PB+PB_LIN2, WF+OFF_LIN2B,
                                        WF+OFF_LN3G, WF+OFF_LN3B, d_out, ln1g_raw);
}

// Round 23
// 185.171 us; speedup vs baseline: 1.0219x; 1.0219x over previous
//
#include <hip/hip_runtime.h>
#include <hip/hip_bf16.h>
#include <math.h>

typedef __hip_bfloat16 bf16;
typedef __attribute__((ext_vector_type(8))) short bf16x8;
typedef __attribute__((ext_vector_type(4))) float f32x4;

#define N_    2
#define D_    192
#define T_    8
#define H_    48
#define W_    48
#define HW_   2304
#define NPOS  36864
#define BUF_ELEMS 7077888    // NPOS*192

// WF (f32 weight arena) element offsets
#define OFF_SOFFW 0
#define OFF_SOFFB 12288
#define OFF_SAWW  12352
#define OFF_SAWB  18496
#define OFF_SVW   18528
#define OFF_SVB   55392
#define OFF_SOW   55584
#define OFF_SOB   92448
#define OFF_TOFFW 92640
#define OFF_TOFFB 98784
#define OFF_TAWW  98816
#define OFF_TAWB  104960
#define OFF_TVW   104992
#define OFF_TVB   141856
#define OFF_TOW   142048
#define OFF_TOB   178912
#define OFF_LN1G  179104
#define OFF_LN1B  179296
#define OFF_LN2G  179488
#define OFF_LN2B  179680
#define OFF_LN3G  179872
#define OFF_LN3B  180064
#define OFF_LIN1W 180256
#define OFF_LIN1B 253984
#define OFF_LIN2W 254176
#define OFF_LIN2B 291040
#define OFF_CONVB 291232
#define WF_TOTAL  291424

// packed-B arena (bf16 elements) offsets
#define PB_SCOMB 0         // 192x288 (v|off|aw)
#define PB_SOW   55296     // 192x192
#define PB_TCOMB 92160     // 192x256 (v|off|aw)
#define PB_TOW   141312
#define PB_LIN1  178176    // 384x192
#define PB_CONV  251904    // 384x192
#define PB_LIN2  325632    // 192x192
#define PB_TOTAL 362496

static __device__ __forceinline__ float b2f(bf16 v){ return __bfloat162float(v); }
static __device__ __forceinline__ bf16  f2b(float v){ return __float2bfloat16(v); }
static __device__ __forceinline__ float lo16(unsigned u){
  unsigned v = u<<16; return *(float*)&v;
}
static __device__ __forceinline__ float hi16(unsigned u){
  unsigned v = u & 0xFFFF0000u; return *(float*)&v;
}
static __device__ __forceinline__ unsigned pk2(float a, float b){
  bf16 x = f2b(a), y = f2b(b);
  return (unsigned)*(unsigned short*)&x | ((unsigned)*(unsigned short*)&y << 16);
}
static __device__ __forceinline__ int detect_bf(const void* ln1g){
  unsigned u = *(const unsigned*)ln1g;
  return __builtin_amdgcn_readfirstlane(((u & 0xFFFFu) != 0u) ? 1 : 0);
}
// 16B-chunk XOR swizzle
static __device__ __forceinline__ int swz8(int ch, int r){ return ch ^ (r & 7); }

// ---- convert all weights (27 regions) to f32 arena; 1 elem/thread ----
struct KPtrs { const void* p[27]; };
static __device__ const int WSZ[27] = {12288,64,6144,32,36864,192,36864,192,
  6144,32,6144,32,36864,192,36864,192, 192,192,192,192,192,192, 73728,192,36864,192, 192};

__global__ void k_cvtw(KPtrs P, float* __restrict__ WF, const void* __restrict__ ln1g){
  int bf = detect_bf(ln1g);
  int gid = blockIdx.x*256 + threadIdx.x;
  if (gid >= WF_TOTAL) return;
  int e = 0, off = 0;
  while (gid >= off + WSZ[e]){ off += WSZ[e]; ++e; }
  int i = gid - off;
  WF[gid] = bf ? b2f(((const bf16*)P.p[e])[i]) : ((const float*)P.p[e])[i];
}

// ---- pack B fragments for 7 matrices; conv_w read directly (transposed index) ----
__global__ void k_packB(const float* __restrict__ WF, const void* __restrict__ convw,
                        bf16* __restrict__ PB, const void* __restrict__ ln1g){
  const int NB[7]  = {108,72,96,72,144,144,72};
  const int NT[7]  = {18,12,16,12,12,12,12};
  const int DST[7] = {PB_SCOMB, PB_SOW, PB_TCOMB, PB_TOW, PB_LIN1, PB_CONV, PB_LIN2};
  int bf = detect_bf(ln1g);
  int bid = blockIdx.x, e = 0, start = 0;
  while (e < 6 && bid >= start + NB[e]){ start += NB[e]; ++e; }
  int local = bid - start;
  int nt = local % NT[e], kt = local / NT[e];
  int l = threadIdx.x;
  int k0 = kt*32 + (l>>4)*8, n0 = nt*16 + (l&15);
  bf16* D = PB + DST[e] + ((long)(kt*NT[e]+nt)*64 + l)*8;
  #pragma unroll
  for (int i=0;i<8;++i){
    int k = k0 + i;
    float v;
    if (e==0){
      if (n0<192)      v = WF[OFF_SVW  + k*192 + n0];
      else if (n0<256) v = WF[OFF_SOFFW+ k*64  + (n0-192)];
      else             v = WF[OFF_SAWW + k*32  + (n0-256)];
    } else if (e==1)   v = WF[OFF_SOW  + k*192 + n0];
    else if (e==2){
      if (n0<192)      v = WF[OFF_TVW  + k*192 + n0];
      else if (n0<224) v = WF[OFF_TOFFW+ k*32  + (n0-192)];
      else             v = WF[OFF_TAWW + k*32  + (n0-224)];
    } else if (e==3)   v = WF[OFF_TOW  + k*192 + n0];
    else if (e==4)     v = WF[OFF_LIN1W+ k*192 + n0];
    else if (e==5)     v = bf ? b2f(((const bf16*)convw)[(long)n0*384 + k])
                              : ((const float*)convw)[(long)n0*384 + k];
    else               v = WF[OFF_LIN2W+ k*192 + n0];
    D[i] = f2b(v);
  }
}

// ---- MFMA GEMM (lin1): LDS-staged swizzled A; MODE 1 = FFN gather + GELU ----
template<int KTOT, int MODE, int CF32>
__global__ void __launch_bounds__(256) k_gemm(const bf16* __restrict__ A0, const bf16* __restrict__ A1,
      const bf16* __restrict__ Bp, const float* __restrict__ bias, void* __restrict__ C_){
  __shared__ bf16 sA[64*KTOT];
  const int NCH = KTOT/8;
  int tid = threadIdx.x;
  int r0 = blockIdx.x*64;
  for (int i=tid; i<64*NCH; i+=256){
    int r = i/NCH, ch = i - r*NCH;
    int grow;
    if (MODE==1){
      int q = r0+r, f = q>>1, n2 = q&1;
      int t2 = f/HW_, hw2 = f - t2*HW_;
      grow = hw2*16 + t2*2 + n2;
    } else grow = r0+r;
    const bf16* src = (MODE==1 && ch>=24) ? (A1 + (long)grow*192 + (ch-24)*8)
                                          : (A0 + (long)grow*192 + ch*8);
    *(bf16x8*)(sA + r*KTOT + swz8(ch,r)*8) = *(const bf16x8*)src;
  }
  __syncthreads();
  int wid = tid>>6, lane = tid&63;
  int m16 = lane&15, kg = lane>>4;
  f32x4 acc[4][3];
  #pragma unroll
  for (int mi=0;mi<4;++mi)
    #pragma unroll
    for (int ni=0;ni<3;++ni) acc[mi][ni] = (f32x4){0.f,0.f,0.f,0.f};

  const int NKT = KTOT/32;
  for (int kt=0; kt<NKT; ++kt){
    bf16x8 b[3];
    #pragma unroll
    for (int ni=0;ni<3;++ni){
      int nt = wid*3 + ni;
      b[ni] = *(const bf16x8*)(Bp + ((long)(kt*12+nt)*64 + lane)*8);
    }
    bf16x8 a[4];
    #pragma unroll
    for (int mi=0;mi<4;++mi){
      int row = mi*16 + m16;
      a[mi] = *(const bf16x8*)(sA + row*KTOT + swz8(kt*4+kg,row)*8);
    }
    #pragma unroll
    for (int mi=0;mi<4;++mi)
      #pragma unroll
      for (int ni=0;ni<3;++ni)
        acc[mi][ni] = __builtin_amdgcn_mfma_f32_16x16x32_bf16(a[mi], b[ni], acc[mi][ni], 0,0,0);
  }
  const float IS2 = 0.70710678118654752f;
  #pragma unroll
  for (int mi=0;mi<4;++mi)
    #pragma unroll
    for (int ni=0;ni<3;++ni){
      int col = (wid*3+ni)*16 + m16;
      float bv = bias[col];
      #pragma unroll
      for (int rg=0;rg<4;++rg){
        int row = r0 + mi*16 + kg*4 + rg;
        float v = acc[mi][ni][rg] + bv;
        if (MODE==1) v = 0.5f*v*(1.f+erff(v*IS2));
        if (CF32) ((float*)C_)[(long)row*192 + col] = v;
        else      ((bf16*)C_)[(long)row*192 + col] = f2b(v);
      }
    }
}

// ---- combined MFMA GEMM (spatial): LDS-staged f32 A; V + off/aw logits ----
template<int NWAVES, int NTW, int NO>
__global__ void __launch_bounds__(NWAVES*64) k_gemmC(const float* __restrict__ A,
      const bf16* __restrict__ Bp, const float* __restrict__ biasV,
      const float* __restrict__ biasO, const float* __restrict__ biasA,
      bf16* __restrict__ Cv, float* __restrict__ Coa){
  __shared__ bf16 sA[64*192];
  const int NT_TOT = NWAVES*NTW;
  const int NOA = NT_TOT*16 - 192;
  int tid = threadIdx.x;
  int r0 = blockIdx.x*64;
  for (int i=tid; i<64*48; i+=NWAVES*64){
    int r = i/48, c4 = i - r*48;
    float4 v = *(const float4*)(A + (long)(r0+r)*192 + c4*4);
    bf16* dst = sA + r*192 + swz8(c4>>1, r)*8 + (c4&1)*4;
    dst[0]=f2b(v.x); dst[1]=f2b(v.y); dst[2]=f2b(v.z); dst[3]=f2b(v.w);
  }
  __syncthreads();
  int wid = tid>>6, lane = tid&63;
  int m16 = lane&15, kg = lane>>4;
  f32x4 acc[4][NTW];
  #pragma unroll
  for (int mi=0;mi<4;++mi)
    #pragma unroll
    for (int ni=0;ni<NTW;++ni) acc[mi][ni] = (f32x4){0.f,0.f,0.f,0.f};
  for (int kt=0; kt<6; ++kt){
    bf16x8 b[NTW];
    #pragma unroll
    for (int ni=0;ni<NTW;++ni){
      int nt = wid*NTW + ni;
      b[ni] = *(const bf16x8*)(Bp + ((long)(kt*NT_TOT+nt)*64 + lane)*8);
    }
    bf16x8 a[4];
    #pragma unroll
    for (int mi=0;mi<4;++mi){
      int row = mi*16 + m16;
      a[mi] = *(const bf16x8*)(sA + row*192 + swz8(kt*4+kg,row)*8);
    }
    #pragma unroll
    for (int mi=0;mi<4;++mi)
      #pragma unroll
      for (int ni=0;ni<NTW;++ni)
        acc[mi][ni] = __builtin_amdgcn_mfma_f32_16x16x32_bf16(a[mi], b[ni], acc[mi][ni], 0,0,0);
  }
  #pragma unroll
  for (int mi=0;mi<4;++mi)
    #pragma unroll
    for (int ni=0;ni<NTW;++ni){
      int col = (wid*NTW+ni)*16 + m16;
      #pragma unroll
      for (int rg=0;rg<4;++rg){
        int row = r0 + mi*16 + kg*4 + rg;
        float v = acc[mi][ni][rg];
        if (col < 192)           Cv[(long)row*192 + col] = f2b(v + biasV[col]);
        else if (col < 192+NO)   Coa[(long)row*NOA + (col-192)] = v + biasO[col-192];
        else                     Coa[(long)row*NOA + (col-192)] = v + biasA[col-192-NO];
      }
    }
}

// ---- conv as MFMA GEMM ----
__global__ void __launch_bounds__(256) k_convm(const void* __restrict__ x, const void* __restrict__ fuse,
      const bf16* __restrict__ Bp, const float* __restrict__ bias, float* __restrict__ B0,
      const void* __restrict__ ln1g){
  __shared__ bf16 sA[64*384];
  int bf = detect_bf(ln1g);
  int bid = blockIdx.x;
  int n = bid/(8*36), rm = bid%(8*36);
  int t = rm/36, hb = rm%36;
  int hw0 = hb*64;
  int tid = threadIdx.x;
  if (bf){
    for (int i=tid; i<384*64; i+=256){
      int c = i>>6, j = i&63;
      long idx = (c<192) ? ((long)((n*192+c)*8 + t)*HW_ + hw0 + j)
                         : ((long)(n*192+(c-192))*HW_ + hw0 + j);
      bf16 v = ((const bf16*)((c<192)?x:fuse))[idx];
      sA[j*384 + swz8(c>>3, j)*8 + (c&7)] = v;
    }
  } else {
    for (int i=tid; i<384*64; i+=256){
      int c = i>>6, j = i&63;
      long idx = (c<192) ? ((long)((n*192+c)*8 + t)*HW_ + hw0 + j)
                         : ((long)(n*192+(c-192))*HW_ + hw0 + j);
      float v = ((const float*)((c<192)?x:fuse))[idx];
      sA[j*384 + swz8(c>>3, j)*8 + (c&7)] = f2b(v);
    }
  }
  __syncthreads();
  int wid = tid>>6, lane = tid&63;
  int m16 = lane&15, kg = lane>>4;
  f32x4 acc[4][3];
  #pragma unroll
  for (int mi=0;mi<4;++mi)
    #pragma unroll
    for (int ni=0;ni<3;++ni) acc[mi][ni] = (f32x4){0.f,0.f,0.f,0.f};
  for (int kt=0; kt<12; ++kt){
    bf16x8 b[3];
    #pragma unroll
    for (int ni=0;ni<3;++ni){
      int nt = wid*3 + ni;
      b[ni] = *(const bf16x8*)(Bp + ((long)(kt*12+nt)*64 + lane)*8);
    }
    bf16x8 a[4];
    #pragma unroll
    for (int mi=0;mi<4;++mi){
      int row = mi*16 + m16;
      a[mi] = *(const bf16x8*)(&sA[row*384 + swz8(kt*4+kg,row)*8]);
    }
    #pragma unroll
    for (int mi=0;mi<4;++mi)
      #pragma unroll
      for (int ni=0;ni<3;++ni)
        acc[mi][ni] = __builtin_amdgcn_mfma_f32_16x16x32_bf16(a[mi], b[ni], acc[mi][ni], 0,0,0);
  }
  long posbase = (long)(n*8+t)*HW_ + hw0;
  #pragma unroll
  for (int mi=0;mi<4;++mi)
    #pragma unroll
    for (int ni=0;ni<3;++ni){
      int col = (wid*3+ni)*16 + m16;
      float bv = bias[col];
      #pragma unroll
      for (int rg=0;rg<4;++rg){
        int row = mi*16 + kg*4 + rg;
        B0[(posbase + row)*192 + col] = acc[mi][ni][rg] + bv;
      }
    }
}

// ---- fused spatial tail: sampling + o-proj MFMA + residual + LN -> XS ----
__global__ void __launch_bounds__(256) k_sfuse(const float* __restrict__ OA, const bf16* __restrict__ V,
    const bf16* __restrict__ Bp, const float* __restrict__ biasO,
    const float* __restrict__ X, const float* __restrict__ g, const float* __restrict__ bta,
    bf16* __restrict__ outXS){
  __shared__ char smem[32768 + 12288];   // tup(32KB)|yb(24.7KB alias) + sA(12KB)
  __shared__ float mrs[32][2];
  float (*tup)[8] = (float(*)[8])smem;
  float (*yb)[193] = (float(*)[193])smem;
  bf16* sA = (bf16*)(smem + 32768);
  int r0 = blockIdx.x*32, tid = threadIdx.x;
  int nt = r0 / HW_;
  for (int i=tid; i<512; i+=256){
    int row = i>>4, head = i&15;
    int l = (r0+row) % HW_;
    int iy = l/48, jx = l%48;
    const float* oa = OA + (long)(r0+row)*96;
    float l0 = oa[64+head*2], l1 = oa[64+head*2+1];
    float m = fmaxf(l0,l1);
    float e0 = __expf(l0-m), e1 = __expf(l1-m);
    float inv = 1.f/(e0+e1);
    const float SC = 48.0f/47.0f;
    #pragma unroll
    for (int p=0;p<2;++p){
      float aw = (p==0?e0:e1)*inv;
      float fx = iy*SC + oa[head*4+p*2+0] - 0.5f;
      float fy = jx*SC + oa[head*4+p*2+1] - 0.5f;
      float x0f = floorf(fx), y0f = floorf(fy);
      float wx = fx-x0f, wy = fy-y0f;
      int x0 = (int)x0f, y0 = (int)y0f;
      int x1 = x0+1, y1 = y0+1;
      bool vx0 = (x0>=0 && x0<48), vx1 = (x1>=0 && x1<48);
      bool vy0 = (y0>=0 && y0<48), vy1 = (y1>=0 && y1<48);
      int cx0 = min(max(x0,0),47), cx1 = min(max(x1,0),47);
      int cy0 = min(max(y0,0),47), cy1 = min(max(y1,0),47);
      float* tp = tup[row*32 + head*2 + p];
      tp[0] = (vx0&&vy0) ? aw*(1.f-wx)*(1.f-wy) : 0.f;
      tp[1] = (vx1&&vy0) ? aw*wx*(1.f-wy)       : 0.f;
      tp[2] = (vx0&&vy1) ? aw*(1.f-wx)*wy       : 0.f;
      tp[3] = (vx1&&vy1) ? aw*wx*wy             : 0.f;
      tp[4] = (float)(cy0*48+cx0);
      tp[5] = (float)(cy0*48+cx1);
      tp[6] = (float)(cy1*48+cx0);
      tp[7] = (float)(cy1*48+cx1);
    }
  }
  __syncthreads();
  const unsigned* vbu = (const unsigned*)(V + (long)nt*HW_*192);
  for (int it=tid; it<3072; it+=256){
    int row = it/96, cp = it - row*96;
    int head = cp/6;
    float a0 = 0.f, a1 = 0.f;
    #pragma unroll
    for (int p=0;p<2;++p){
      const float* tp = tup[row*32 + head*2 + p];
      #pragma unroll
      for (int c=0;c<4;++c){
        float w = tp[c];
        int idx = (int)tp[4+c];
        unsigned u = vbu[idx*96 + cp];
        a0 += w*lo16(u);
        a1 += w*hi16(u);
      }
    }
    *(unsigned*)(sA + row*192 + swz8(cp>>2,row)*8 + (cp&3)*2) = pk2(a0,a1);
  }
  __syncthreads();
  int wid = tid>>6, lane = tid&63;
  int m16 = lane&15, kg = lane>>4;
  f32x4 acc[2][3];
  #pragma unroll
  for (int mi=0;mi<2;++mi)
    #pragma unroll
    for (int ni=0;ni<3;++ni) acc[mi][ni] = (f32x4){0.f,0.f,0.f,0.f};
  for (int kt=0; kt<6; ++kt){
    bf16x8 b[3];
    #pragma unroll
    for (int ni=0;ni<3;++ni){
      int ntb = wid*3 + ni;
      b[ni] = *(const bf16x8*)(Bp + ((long)(kt*12+ntb)*64 + lane)*8);
    }
    bf16x8 a[2];
    #pragma unroll
    for (int mi=0;mi<2;++mi){
      int row = mi*16 + m16;
      a[mi] = *(const bf16x8*)(sA + row*192 + swz8(kt*4+kg,row)*8);
    }
    #pragma unroll
    for (int mi=0;mi<2;++mi)
      #pragma unroll
      for (int ni=0;ni<3;++ni)
        acc[mi][ni] = __builtin_amdgcn_mfma_f32_16x16x32_bf16(a[mi], b[ni], acc[mi][ni], 0,0,0);
  }
  __syncthreads();
  #pragma unroll
  for (int mi=0;mi<2;++mi)
    #pragma unroll
    for (int ni=0;ni<3;++ni){
      int col = (wid*3+ni)*16 + m16;
      float bv = biasO[col];
      #pragma unroll
      for (int rg=0;rg<4;++rg){
        int lr = mi*16 + kg*4 + rg;
        yb[lr][col] = acc[mi][ni][rg] + bv + X[(long)(r0+lr)*192 + col];
      }
    }
  __syncthreads();
  for (int rr=0; rr<8; ++rr){
    int row = wid*8 + rr;
    float s=0.f, s2=0.f;
    #pragma unroll
    for (int e=0;e<3;++e){
      float v = yb[row][lane*3+e];
      s += v; s2 += v*v;
    }
    #pragma unroll
    for (int off=32; off>0; off>>=1){ s += __shfl_xor(s,off); s2 += __shfl_xor(s2,off); }
    if (lane==0){
      float mean = s*(1.f/192.f);
      mrs[row][0] = mean;
      mrs[row][1] = rsqrtf(s2*(1.f/192.f) - mean*mean + 1e-5f);
    }
  }
  __syncthreads();
  for (int i=tid; i<3072; i+=256){
    int row = i/96, cp = i - row*96;
    float mean = mrs[row][0], rstd = mrs[row][1];
    int c0 = cp*2, c1 = c0+1;
    float v0 = (yb[row][c0]-mean)*rstd*g[c0] + bta[c0];
    float v1 = (yb[row][c1]-mean)*rstd*g[c1] + bta[c1];
    ((unsigned*)outXS)[(long)(r0+row)*96 + cp] = pk2(v0,v1);
  }
}

// ---- full temporal path, 2-token tile (16 rows), ~24.6KB LDS (round-21 version) ----
__global__ void __launch_bounds__(256) k_tpath(const float* __restrict__ S0,
    const bf16* __restrict__ BpC, const float* __restrict__ biasV,
    const float* __restrict__ biasOf, const float* __restrict__ biasAw,
    const bf16* __restrict__ BpO, const float* __restrict__ biasO,
    const float* __restrict__ g, const float* __restrict__ bta,
    bf16* __restrict__ outXT){
  __shared__ char smem[24576];
  __shared__ float mrs[16][2];
  float*    srcF = (float*)smem;                    // [2][8][192] linear
  bf16*     sST  = (bf16*)(smem + 12288);           // sXT then sA, 6K
  bf16*     sV   = (bf16*)smem;                     // stride 200, [0,6400)
  float*    slog = (float*)(smem + 6400);           // stride 68, 16 rows
  float (*tup)[3] = (float(*)[3])(smem + 18432);    // [512][3]
  float*    yb   = (float*)smem;                    // [16][192] post-E
  float*    srcF2= (float*)(smem + 12288);          // [2][8][192] post-E
  int bid = blockIdx.x, tid = threadIdx.x;
  int b0 = bid*2, r0 = bid*16;
  int n = b0 / HW_, hw0 = b0 - n*HW_;
  int wid = tid>>6, lane = tid&63;
  int m16 = lane&15, kg = lane>>4;

  // phase A1: coalesced float4 stage of S0 source rows (linear layout)
  for (int i=tid; i<768; i+=256){
    int j = i/384, rem = i - j*384;
    int t = rem/48, c4 = rem - t*48;
    float4 v = *(const float4*)(S0 + ((long)((n*8+t)*HW_) + hw0+j)*192 + c4*4);
    *(float4*)(srcF + j*1536 + t*192 + c4*4) = v;
  }
  __syncthreads();
  // phase A2: transposed vectorized write to swizzled sST (x_temp bf16)
  for (int idx=tid; idx<384; idx+=256){
    int lrow = idx/24, ch = idx - lrow*24;
    int j = lrow>>3, tau = lrow&7;
    int o = tau*24 + ch;
    const float* sp = srcF + j*1536 + o;
    union { bf16 h[8]; bf16x8 v; } u;
    #pragma unroll
    for (int t=0;t<8;++t) u.h[t] = f2b(sp[t*192]);
    *(bf16x8*)(sST + lrow*192 + swz8(ch,lrow)*8) = u.v;
  }
  __syncthreads();
  // phase B: MFMA vs TCOMB (V -> sV s200, logits -> slog s68); 16 rows = 1 m-tile
  {
    f32x4 acc[4];
    #pragma unroll
    for (int ni=0;ni<4;++ni) acc[ni] = (f32x4){0.f,0.f,0.f,0.f};
    for (int kt=0; kt<6; ++kt){
      bf16x8 b[4];
      #pragma unroll
      for (int ni=0;ni<4;++ni){
        int ntb = wid*4 + ni;
        b[ni] = *(const bf16x8*)(BpC + ((long)(kt*16+ntb)*64 + lane)*8);
      }
      bf16x8 a = *(const bf16x8*)(sST + m16*192 + swz8(kt*4+kg,m16)*8);
      #pragma unroll
      for (int ni=0;ni<4;++ni)
        acc[ni] = __builtin_amdgcn_mfma_f32_16x16x32_bf16(a, b[ni], acc[ni], 0,0,0);
    }
    __syncthreads();   // srcF reads retired (sV/slog overwrite that slot)
    #pragma unroll
    for (int ni=0;ni<4;++ni){
      int col = (wid*4+ni)*16 + m16;
      #pragma unroll
      for (int rg=0;rg<4;++rg){
        int lr = kg*4 + rg;
        float v = acc[ni][rg];
        if (col < 192)      sV[lr*200 + col] = f2b(v + biasV[col]);
        else if (col < 224) slog[lr*68 + (col-192)] = v + biasOf[col-192];
        else                slog[lr*68 + (col-192)] = v + biasAw[col-224];
      }
    }
  }
  __syncthreads();
  // phase C: coords (16 rows x 8 heads = 128 items)
  if (tid < 128){
    int row = tid>>3, head = tid&7;
    int tau = row & 7;
    float pref = tau*(8.0f/7.0f) - 0.5f;
    const float* ot = slog + row*68;
    float l0=ot[32+head*4], l1=ot[32+head*4+1], l2=ot[32+head*4+2], l3=ot[32+head*4+3];
    float m = fmaxf(fmaxf(l0,l1), fmaxf(l2,l3));
    float e0=__expf(l0-m), e1=__expf(l1-m), e2=__expf(l2-m), e3=__expf(l3-m);
    float inv = 1.f/(e0+e1+e2+e3);
    float ee[4] = {e0,e1,e2,e3};
    #pragma unroll
    for (int p=0;p<4;++p){
      float aw = ee[p]*inv;
      float fp = pref + ot[head*4+p];
      float p0f = floorf(fp);
      float wp = fp - p0f;
      int p0 = (int)p0f, p1 = p0+1;
      float* tp = tup[row*32 + head*4 + p];
      tp[0] = (p0>=0 && p0<8) ? aw*(1.f-wp) : 0.f;
      tp[1] = (p1>=0 && p1<8) ? aw*wp       : 0.f;
      tp[2] = (float)(min(max(p0,0),7)*8 + min(max(p1,0),7));
    }
  }
  __syncthreads();
  // phase D: sampling -> swizzled sA (sST slot)
  {
    const unsigned* sVu = (const unsigned*)sV;   // row stride 100 uints
    for (int it=tid; it<1536; it+=256){
      int row = it/96, cp = it - row*96;
      int head = cp/12;
      const unsigned* vb = sVu + (row>>3)*800;
      float a0 = 0.f, a1 = 0.f;
      #pragma unroll
      for (int p=0;p<4;++p){
        const float* tp = tup[row*32 + head*4 + p];
        int pk = (int)tp[2];
        unsigned u0 = vb[(pk>>3)*100 + cp];
        unsigned u1 = vb[(pk&7)*100 + cp];
        a0 += tp[0]*lo16(u0) + tp[1]*lo16(u1);
        a1 += tp[0]*hi16(u0) + tp[1]*hi16(u1);
      }
      *(unsigned*)(sST + row*192 + swz8(cp>>2,row)*8 + (cp&3)*2) = pk2(a0,a1);
    }
  }
  __syncthreads();
  // phase E: o-proj MFMA
  f32x4 acc2[3];
  #pragma unroll
  for (int ni=0;ni<3;++ni) acc2[ni] = (f32x4){0.f,0.f,0.f,0.f};
  for (int kt=0; kt<6; ++kt){
    bf16x8 b[3];
    #pragma unroll
    for (int ni=0;ni<3;++ni){
      int ntb = wid*3 + ni;
      b[ni] = *(const bf16x8*)(BpO + ((long)(kt*12+ntb)*64 + lane)*8);
    }
    bf16x8 a = *(const bf16x8*)(sST + m16*192 + swz8(kt*4+kg,m16)*8);
    #pragma unroll
    for (int ni=0;ni<3;++ni)
      acc2[ni] = __builtin_amdgcn_mfma_f32_16x16x32_bf16(a, b[ni], acc2[ni], 0,0,0);
  }
  __syncthreads();   // all earlier regions dead
  // phase F1: coalesced re-stage of S0 into srcF2
  for (int i=tid; i<768; i+=256){
    int j = i/384, rem = i - j*384;
    int t = rem/48, c4 = rem - t*48;
    float4 v = *(const float4*)(S0 + ((long)((n*8+t)*HW_) + hw0+j)*192 + c4*4);
    *(float4*)(srcF2 + j*1536 + t*192 + c4*4) = v;
  }
  __syncthreads();
  // phase F2: transposed residual into yb [16][192]
  for (int idx=tid; idx<384; idx+=256){
    int lrow = idx/24, ch = idx - lrow*24;
    int j = lrow>>3, tau = lrow&7;
    int o = tau*24 + ch;
    const float* sp = srcF2 + j*1536 + o;
    float* dp = yb + lrow*192 + ch*8;
    #pragma unroll
    for (int t=0;t<8;++t) dp[t] = sp[t*192];
  }
  __syncthreads();
  // add o-proj + bias
  #pragma unroll
  for (int ni=0;ni<3;++ni){
    int col = (wid*3+ni)*16 + m16;
    float bv = biasO[col];
    #pragma unroll
    for (int rg=0;rg<4;++rg){
      int lr = kg*4 + rg;
      yb[lr*192 + col] += acc2[ni][rg] + bv;
    }
  }
  __syncthreads();
  // phase G: LN + write XT
  for (int rr=0; rr<4; ++rr){
    int row = wid*4 + rr;
    float s=0.f, s2=0.f;
    #pragma unroll
    for (int e=0;e<3;++e){
      float v = yb[row*192 + lane*3+e];
      s += v; s2 += v*v;
    }
    #pragma unroll
    for (int off=32; off>0; off>>=1){ s += __shfl_xor(s,off); s2 += __shfl_xor(s2,off); }
    if (lane==0){
      float mean = s*(1.f/192.f);
      mrs[row][0] = mean;
      mrs[row][1] = rsqrtf(s2*(1.f/192.f) - mean*mean + 1e-5f);
    }
  }
  __syncthreads();
  for (int i=tid; i<1536; i+=256){
    int row = i/96, cp = i - row*96;
    float mean = mrs[row][0], rstd = mrs[row][1];
    int c0 = cp*2, c1 = c0+1;
    float v0 = (yb[row*192+c0]-mean)*rstd*g[c0] + bta[c0];
    float v1 = (yb[row*192+c1]-mean)*rstd*g[c1] + bta[c1];
    ((unsigned*)outXT)[(long)(r0+row)*96 + cp] = pk2(v0,v1);
  }
}

// ---- final fused: 32 pos/block; bf16 hid staged; MFMA lin2 + residual + LN + scatter ----
__global__ void __launch_bounds__(256) k_final3(const float* __restrict__ B0, const bf16* __restrict__ hid,
    const bf16* __restrict__ Bp, const float* __restrict__ bias2,
    const float* __restrict__ g, const float* __restrict__ bta,
    void* __restrict__ out, const void* __restrict__ ln1g){
  __shared__ float yb[32][193];
  __shared__ float mrs[32][2];
  bf16* sA = (bf16*)&yb[0][0];
  int bf = detect_bf(ln1g);
  int pos0 = blockIdx.x*32;
  int tid = threadIdx.x, wid = tid>>6, lane = tid&63;
  int m16 = lane&15, kg = lane>>4;
  int n2 = pos0/(T_*HW_), rem0 = pos0%(T_*HW_);
  long qrow0 = (long)rem0*2 + n2;
  for (int i=tid; i<32*24; i+=256){
    int r = i/24, ch = i - r*24;
    *(bf16x8*)(sA + r*192 + swz8(ch,r)*8) =
        *(const bf16x8*)(hid + (qrow0 + r*2)*192 + ch*8);
  }
  __syncthreads();
  f32x4 acc[2][3];
  #pragma unroll
  for (int mi=0;mi<2;++mi)
    #pragma unroll
    for (int ni=0;ni<3;++ni) acc[mi][ni] = (f32x4){0.f,0.f,0.f,0.f};
  for (int kt=0; kt<6; ++kt){
    bf16x8 b[3];
    #pragma unroll
    for (int ni=0;ni<3;++ni){
      int nt = wid*3 + ni;
      b[ni] = *(const bf16x8*)(Bp + ((long)(kt*12+nt)*64 + lane)*8);
    }
    bf16x8 a[2];
    #pragma unroll
    for (int mi=0;mi<2;++mi){
      int row = mi*16 + m16;
      a[mi] = *(const bf16x8*)(sA + row*192 + swz8(kt*4+kg,row)*8);
    }
    #pragma unroll
    for (int mi=0;mi<2;++mi)
      #pragma unroll
      for (int ni=0;ni<3;++ni)
        acc[mi][ni] = __builtin_amdgcn_mfma_f32_16x16x32_bf16(a[mi], b[ni], acc[mi][ni], 0,0,0);
  }
  __syncthreads();
  #pragma unroll
  for (int mi=0;mi<2;++mi)
    #pragma unroll
    for (int ni=0;ni<3;++ni){
      int col = (wid*3+ni)*16 + m16;
      float bv = bias2[col];
      #pragma unroll
      for (int rg=0;rg<4;++rg){
        int lr = mi*16 + kg*4 + rg;
        yb[lr][col] = acc[mi][ni][rg] + bv + B0[(long)(pos0+lr)*192 + col];
      }
    }
  __syncthreads();
  for (int rr=0; rr<8; ++rr){
    int row = wid*8 + rr;
    float s=0.f, s2=0.f;
    #pragma unroll
    for (int e=0;e<3;++e){
      float v = yb[row][lane*3+e];
      s += v; s2 += v*v;
    }
    #pragma unroll
    for (int off=32; off>0; off>>=1){ s += __shfl_xor(s,off); s2 += __shfl_xor(s2,off); }
    if (lane==0){
      float mean = s*(1.f/192.f);
      mrs[row][0] = mean;
      mrs[row][1] = rsqrtf(s2*(1.f/192.f) - mean*mean + 1e-5f);
    }
  }
  __syncthreads();
  int t2 = rem0/HW_, hw0 = rem0%HW_;
  int j = lane & 31;
  float mean = mrs[j][0], rstd = mrs[j][1];
  for (int cc=0; cc<48; cc+=2){
    int c = wid*48 + cc + (lane>>5);
    float val = (yb[j][c]-mean)*rstd*g[c] + bta[c];
    long idx = ((long)(n2*192 + c)*8 + t2)*HW_ + hw0 + j;
    if (bf) ((bf16*)out)[idx] = f2b(val);
    else    ((float*)out)[idx] = val;
  }
}

extern "C" void kernel_launch(void* const* d_in, const int* in_sizes, int n_in,
                              void* d_out, int out_size, void* d_ws, size_t ws_size,
                              hipStream_t stream){
  const void* x      = d_in[0];
  const void* fuse   = d_in[1];
  const void* conv_w = d_in[2];
  const void* ln1g_raw = d_in[20];

  float* S0f = (float*)d_ws;
  float* WS2 = S0f + BUF_ELEMS;          // Vb bf16 (1st half) + OA f32 (2nd half); HID aliases
  bf16*  Vb  = (bf16*)WS2;
  float* OA  = WS2 + BUF_ELEMS/2;
  bf16*  HID = (bf16*)WS2;
  float* WS4 = WS2 + BUF_ELEMS;          // XS
  bf16*  XS  = (bf16*)WS4;
  float* WS5 = WS4 + BUF_ELEMS/2;        // XT
  bf16*  XT  = (bf16*)WS5;
  float* WF  = WS5 + BUF_ELEMS/2;
  bf16*  PB  = (bf16*)(WF + WF_TOTAL);

  KPtrs P;
  for (int i=0;i<26;++i) P.p[i] = d_in[4+i];
  P.p[26] = d_in[3];   // conv_b

  k_cvtw <<<(WF_TOTAL+255)/256, 256, 0, stream>>>(P, WF, ln1g_raw);
  k_packB<<<708, 64, 0, stream>>>(WF, conv_w, PB, ln1g_raw);

  k_convm<<<576, 256, 0, stream>>>(x, fuse, PB+PB_CONV, WF+OFF_CONVB, S0f, ln1g_raw);

  // spatial deformable attention
  k_gemmC<6,3,64><<<576, 384, 0, stream>>>(S0f, PB+PB_SCOMB, WF+OFF_SVB, WF+OFF_SOFFB, WF+OFF_SAWB, Vb, OA);
  k_sfuse<<<NPOS/32, 256, 0, stream>>>(OA, Vb, PB+PB_SOW, WF+OFF_SOB, S0f,
                                       WF+OFF_LN1G, WF+OFF_LN1B, XS);

  // temporal deformable attention: single fused kernel, 2-token tiles
  k_tpath<<<NPOS/16, 256, 0, stream>>>(S0f, PB+PB_TCOMB, WF+OFF_TVB, WF+OFF_TOFFB, WF+OFF_TAWB,
                                       PB+PB_TOW, WF+OFF_TOB, WF+OFF_LN2G, WF+OFF_LN2B, XT);

  // FFN (gather + GELU, bf16 out) + fused final
  k_gemm<384,1,0><<<576, 256, 0, stream>>>(XT, XS, PB+PB_LIN1, WF+OFF_LIN1B, HID);
  k_final3<<<NPOS/32, 256, 0, stream>>>(S0f, HID, PB+PB_LIN2, WF+OFF_LIN2B,
                                        WF+OFF_LN3G, WF+OFF_LN3B, d_out, ln1g_raw);
}